// Round 2
// baseline (1060.097 us; speedup 1.0000x reference)
//
#include <hip/hip_runtime.h>

#define TEMP 10.0f

typedef float v2f __attribute__((ext_vector_type(2)));

// Packed f32x2 atomic add (global_atomic_pk_add_f32). One transaction for two
// floats instead of two. Falls back to scalar atomics if builtin missing.
__device__ __forceinline__ void pk_fadd(float* p, float a, float b) {
#if __has_builtin(__builtin_amdgcn_global_atomic_fadd_v2f32)
    v2f v; v.x = a; v.y = b;
    __builtin_amdgcn_global_atomic_fadd_v2f32(
        (__attribute__((address_space(1))) v2f*)p, v);
#else
    atomicAdd(p, a);
    atomicAdd(p + 1, b);
#endif
}

// ws layout: per-node record of 6 floats (24B, 8B-aligned):
//   rec[0]=Z  rec[1]=sum(p*l)  rec[2..5]=sum(p*q)
__global__ void __launch_bounds__(256)
spt_edge_kernel(const float* __restrict__ node_levels,
                const float4* __restrict__ node_q,
                const float4* __restrict__ edge_rel_q,
                const float* __restrict__ edge_w,
                const int* __restrict__ src,
                const int* __restrict__ dst,
                float* __restrict__ wsRec,
                int E) {
    int e = blockIdx.x * blockDim.x + threadIdx.x;
    if (e >= E) return;

    int s = src[e];
    int d = dst[e];
    float l = node_levels[s];
    float w = edge_w[e];
    float p = __expf(TEMP * w * l);     // unnormalized softmax weight; cost in [0,10)

    float4 a = edge_rel_q[e];           // (w,x,y,z)
    float4 b = node_q[s];

    // Hamilton product a*b
    float ow = a.x*b.x - a.y*b.y - a.z*b.z - a.w*b.w;
    float ox = a.x*b.y + a.y*b.x + a.z*b.w - a.w*b.z;
    float oy = a.x*b.z - a.y*b.w + a.z*b.x + a.w*b.y;
    float oz = a.x*b.w + a.y*b.z - a.z*b.y + a.w*b.x;

    float* rec = wsRec + 6 * (long long)d;
    pk_fadd(rec + 0, p,      p * l);
    pk_fadd(rec + 2, p * ow, p * ox);
    pk_fadd(rec + 4, p * oy, p * oz);
}

__global__ void __launch_bounds__(256)
spt_node_kernel(const float* __restrict__ node_levels,
                const float4* __restrict__ node_q,
                const float2* __restrict__ wsRec,   // 3 float2 per node
                float4* __restrict__ out_q,
                float* __restrict__ out_l,
                int N) {
    int n = blockIdx.x * blockDim.x + threadIdx.x;
    if (n >= N) return;

    float l = node_levels[n];
    float ps = __expf(TEMP * l);        // self term (w = 1)

    float2 zl = wsRec[3 * (long long)n + 0];
    float2 q01 = wsRec[3 * (long long)n + 1];
    float2 q23 = wsRec[3 * (long long)n + 2];

    float Z = zl.x + ps;
    float sl = zl.y + ps * l;

    float4 q = node_q[n];
    float qw = q01.x + ps * q.x;
    float qx = q01.y + ps * q.y;
    float qy = q23.x + ps * q.z;
    float qz = q23.y + ps * q.w;

    float inv = 1.0f / Z;
    qw *= inv; qx *= inv; qy *= inv; qz *= inv;
    float norm = sqrtf(qw*qw + qx*qx + qy*qy + qz*qz);
    norm = fmaxf(norm, 1e-12f);
    float rn = 1.0f / norm;

    out_q[n] = make_float4(qw * rn, qx * rn, qy * rn, qz * rn);
    out_l[n] = sl * inv;
}

extern "C" void kernel_launch(void* const* d_in, const int* in_sizes, int n_in,
                              void* d_out, int out_size, void* d_ws, size_t ws_size,
                              hipStream_t stream) {
    const float*  node_levels = (const float*)d_in[0];
    const float4* node_q      = (const float4*)d_in[1];
    const float4* edge_rel_q  = (const float4*)d_in[2];
    const float*  edge_w      = (const float*)d_in[3];
    const int*    src         = (const int*)d_in[4];
    const int*    dst         = (const int*)d_in[5];

    const int N = in_sizes[0];        // node_levels count
    const int E = in_sizes[3];        // edge_w count

    float* wsRec = (float*)d_ws;      // 6*N floats, same footprint as R1

    hipMemsetAsync(d_ws, 0, (size_t)6 * N * sizeof(float), stream);

    int tpb = 256;
    spt_edge_kernel<<<(E + tpb - 1) / tpb, tpb, 0, stream>>>(
        node_levels, node_q, edge_rel_q, edge_w, src, dst, wsRec, E);

    spt_node_kernel<<<(N + tpb - 1) / tpb, tpb, 0, stream>>>(
        node_levels, node_q, (const float2*)wsRec,
        (float4*)d_out, (float*)d_out + 4 * (long long)N, N);
}

// Round 3
// 572.457 us; speedup vs baseline: 1.8518x; 1.8518x over previous
//
#include <hip/hip_runtime.h>

#define TEMP 10.0f

typedef float v2f __attribute__((ext_vector_type(2)));

__device__ __forceinline__ void pk_fadd(float* p, float a, float b) {
#if __has_builtin(__builtin_amdgcn_global_atomic_fadd_v2f32)
    v2f v; v.x = a; v.y = b;
    __builtin_amdgcn_global_atomic_fadd_v2f32(
        (__attribute__((address_space(1))) v2f*)p, v);
#else
    atomicAdd(p, a);
    atomicAdd(p + 1, b);
#endif
}

__device__ __forceinline__ void hamilton(float4 a, float4 b,
                                         float& ow, float& ox, float& oy, float& oz) {
    ow = a.x*b.x - a.y*b.y - a.z*b.z - a.w*b.w;
    ox = a.x*b.y + a.y*b.x + a.z*b.w - a.w*b.z;
    oy = a.x*b.z - a.y*b.w + a.z*b.x + a.w*b.y;
    oz = a.x*b.w + a.y*b.z - a.z*b.y + a.w*b.x;
}

// ---------------- bucket path ----------------
// ws: cnt[N] int | side[6N] float (pk-atomic overflow accum) | bucket[N*cap] int

__global__ void __launch_bounds__(256)
scatter_kernel(const int* __restrict__ dst,
               int* __restrict__ cnt,
               int* __restrict__ bucket, int cap,
               const float* __restrict__ node_levels,
               const float4* __restrict__ node_q,
               const float4* __restrict__ edge_rel_q,
               const float* __restrict__ edge_w,
               const int* __restrict__ src,
               float* __restrict__ side,
               int E) {
    int e = blockIdx.x * blockDim.x + threadIdx.x;
    if (e >= E) return;
    int d = dst[e];
    int slot = atomicAdd(&cnt[d], 1);
    if (slot < cap) {
        bucket[(long long)d * cap + slot] = e;
    } else {
        // overflow (statistically ~never for cap=128, deg~Poisson(32)); correct path
        int s = src[e];
        float l = node_levels[s];
        float p = __expf(TEMP * edge_w[e] * l);
        float ow, ox, oy, oz;
        hamilton(edge_rel_q[e], node_q[s], ow, ox, oy, oz);
        float* rec = side + 6 * (long long)d;
        pk_fadd(rec + 0, p,      p * l);
        pk_fadd(rec + 2, p * ow, p * ox);
        pk_fadd(rec + 4, p * oy, p * oz);
    }
}

// one 32-lane half-wave per node
__global__ void __launch_bounds__(256)
gather_kernel(const float* __restrict__ node_levels,
              const float4* __restrict__ node_q,
              const float4* __restrict__ edge_rel_q,
              const float* __restrict__ edge_w,
              const int* __restrict__ src,
              const int* __restrict__ cnt,
              const int* __restrict__ bucket, int cap,
              const float* __restrict__ side,
              float4* __restrict__ out_q,
              float* __restrict__ out_l,
              int N) {
    int tid  = blockIdx.x * blockDim.x + threadIdx.x;
    int wave = tid >> 6;
    int lane = tid & 63;
    int half = lane >> 5;
    int sub  = lane & 31;
    int n = wave * 2 + half;

    float aZ = 0.f, aL = 0.f, a0 = 0.f, a1 = 0.f, a2 = 0.f, a3 = 0.f;
    if (n < N) {
        int deg = cnt[n];
        if (deg > cap) deg = cap;
        const int* bkt = bucket + (long long)n * cap;
        for (int s = sub; s < deg; s += 32) {
            int e = bkt[s];
            int sn = src[e];
            float l = node_levels[sn];
            float p = __expf(TEMP * edge_w[e] * l);
            float ow, ox, oy, oz;
            hamilton(edge_rel_q[e], node_q[sn], ow, ox, oy, oz);
            aZ += p;       aL += p * l;
            a0 += p * ow;  a1 += p * ox;
            a2 += p * oy;  a3 += p * oz;
        }
    }
    // butterfly within each 32-lane half (xor masks < 32 stay inside the half)
    for (int m = 16; m; m >>= 1) {
        aZ += __shfl_xor(aZ, m); aL += __shfl_xor(aL, m);
        a0 += __shfl_xor(a0, m); a1 += __shfl_xor(a1, m);
        a2 += __shfl_xor(a2, m); a3 += __shfl_xor(a3, m);
    }
    if (sub == 0 && n < N) {
        const float* rec = side + 6 * (long long)n;
        float l  = node_levels[n];
        float ps = __expf(TEMP * l);
        float Z  = aZ + rec[0] + ps;
        float sl = aL + rec[1] + ps * l;
        float4 q = node_q[n];
        float qw = a0 + rec[2] + ps * q.x;
        float qx = a1 + rec[3] + ps * q.y;
        float qy = a2 + rec[4] + ps * q.z;
        float qz = a3 + rec[5] + ps * q.w;
        float inv = 1.0f / Z;
        qw *= inv; qx *= inv; qy *= inv; qz *= inv;
        float norm = sqrtf(qw*qw + qx*qx + qy*qy + qz*qz);
        norm = fmaxf(norm, 1e-12f);
        float rn = 1.0f / norm;
        out_q[n] = make_float4(qw * rn, qx * rn, qy * rn, qz * rn);
        out_l[n] = sl * inv;
    }
}

// ---------------- fallback atomic path (R2) ----------------

__global__ void __launch_bounds__(256)
spt_edge_kernel(const float* __restrict__ node_levels,
                const float4* __restrict__ node_q,
                const float4* __restrict__ edge_rel_q,
                const float* __restrict__ edge_w,
                const int* __restrict__ src,
                const int* __restrict__ dst,
                float* __restrict__ wsRec,
                int E) {
    int e = blockIdx.x * blockDim.x + threadIdx.x;
    if (e >= E) return;
    int s = src[e];
    int d = dst[e];
    float l = node_levels[s];
    float p = __expf(TEMP * edge_w[e] * l);
    float ow, ox, oy, oz;
    hamilton(edge_rel_q[e], node_q[s], ow, ox, oy, oz);
    float* rec = wsRec + 6 * (long long)d;
    pk_fadd(rec + 0, p,      p * l);
    pk_fadd(rec + 2, p * ow, p * ox);
    pk_fadd(rec + 4, p * oy, p * oz);
}

__global__ void __launch_bounds__(256)
spt_node_kernel(const float* __restrict__ node_levels,
                const float4* __restrict__ node_q,
                const float* __restrict__ wsRec,
                float4* __restrict__ out_q,
                float* __restrict__ out_l,
                int N) {
    int n = blockIdx.x * blockDim.x + threadIdx.x;
    if (n >= N) return;
    const float* rec = wsRec + 6 * (long long)n;
    float l  = node_levels[n];
    float ps = __expf(TEMP * l);
    float Z  = rec[0] + ps;
    float sl = rec[1] + ps * l;
    float4 q = node_q[n];
    float qw = rec[2] + ps * q.x;
    float qx = rec[3] + ps * q.y;
    float qy = rec[4] + ps * q.z;
    float qz = rec[5] + ps * q.w;
    float inv = 1.0f / Z;
    qw *= inv; qx *= inv; qy *= inv; qz *= inv;
    float norm = fmaxf(sqrtf(qw*qw + qx*qx + qy*qy + qz*qz), 1e-12f);
    float rn = 1.0f / norm;
    out_q[n] = make_float4(qw * rn, qx * rn, qy * rn, qz * rn);
    out_l[n] = sl * inv;
}

extern "C" void kernel_launch(void* const* d_in, const int* in_sizes, int n_in,
                              void* d_out, int out_size, void* d_ws, size_t ws_size,
                              hipStream_t stream) {
    const float*  node_levels = (const float*)d_in[0];
    const float4* node_q      = (const float4*)d_in[1];
    const float4* edge_rel_q  = (const float4*)d_in[2];
    const float*  edge_w      = (const float*)d_in[3];
    const int*    src         = (const int*)d_in[4];
    const int*    dst         = (const int*)d_in[5];

    const int N = in_sizes[0];
    const int E = in_sizes[3];
    const int tpb = 256;

    // layout: cnt[N] int | side[6N] float | bucket[N*cap] int
    size_t cnt_elems  = ((size_t)N + 3) & ~(size_t)3;   // 16B-align side
    size_t side_elems = 6 * (size_t)N;
    size_t head_bytes = (cnt_elems + side_elems) * 4;

    int cap = 0;
    for (int c : {128, 64}) {
        if (head_bytes + (size_t)N * c * 4 <= ws_size) { cap = c; break; }
    }

    if (cap) {
        int*   cnt    = (int*)d_ws;
        float* side   = (float*)d_ws + cnt_elems;
        int*   bucket = (int*)d_ws + cnt_elems + side_elems;

        hipMemsetAsync(d_ws, 0, head_bytes, stream);

        scatter_kernel<<<(E + tpb - 1) / tpb, tpb, 0, stream>>>(
            dst, cnt, bucket, cap,
            node_levels, node_q, edge_rel_q, edge_w, src, side, E);

        int waves  = (N + 1) / 2;                 // 2 nodes per wave
        int blocks = (waves * 64 + tpb - 1) / tpb;
        gather_kernel<<<blocks, tpb, 0, stream>>>(
            node_levels, node_q, edge_rel_q, edge_w, src,
            cnt, bucket, cap, side,
            (float4*)d_out, (float*)d_out + 4 * (long long)N, N);
    } else {
        float* wsRec = (float*)d_ws;
        hipMemsetAsync(d_ws, 0, (size_t)6 * N * sizeof(float), stream);
        spt_edge_kernel<<<(E + tpb - 1) / tpb, tpb, 0, stream>>>(
            node_levels, node_q, edge_rel_q, edge_w, src, dst, wsRec, E);
        spt_node_kernel<<<(N + tpb - 1) / tpb, tpb, 0, stream>>>(
            node_levels, node_q, wsRec,
            (float4*)d_out, (float*)d_out + 4 * (long long)N, N);
    }
}

// Round 4
// 387.701 us; speedup vs baseline: 2.7343x; 1.4765x over previous
//
#include <hip/hip_runtime.h>
#include <hip/hip_fp16.h>

#define TEMP 10.0f
#define TPB 256
#define NBLK 256          // scatter/hist blocks (must equal P1 blockDim)
#define SHIFT 7
#define GSZ 128           // nodes per bucket = 1<<SHIFT

typedef float v2f __attribute__((ext_vector_type(2)));

__device__ __forceinline__ void pk_fadd(float* p, float a, float b) {
#if __has_builtin(__builtin_amdgcn_global_atomic_fadd_v2f32)
    v2f v; v.x = a; v.y = b;
    __builtin_amdgcn_global_atomic_fadd_v2f32(
        (__attribute__((address_space(1))) v2f*)p, v);
#else
    atomicAdd(p, a); atomicAdd(p + 1, b);
#endif
}

__device__ __forceinline__ void hamilton(float4 a, float4 b,
                                         float& ow, float& ox, float& oy, float& oz) {
    ow = a.x*b.x - a.y*b.y - a.z*b.z - a.w*b.w;
    ox = a.x*b.y + a.y*b.x + a.z*b.w - a.w*b.z;
    oy = a.x*b.z - a.y*b.w + a.z*b.x + a.w*b.y;
    oz = a.x*b.w + a.y*b.z - a.z*b.y + a.w*b.x;
}

__device__ __forceinline__ unsigned f2h(float x) {
    return (unsigned)__half_as_ushort(__float2half_rn(x));
}
__device__ __forceinline__ float h2f(unsigned u) {
    return __half2float(__ushort_as_half((unsigned short)(u & 0xFFFFu)));
}

// ---------- pass H: per-block LDS histogram of dst buckets ----------
__global__ void __launch_bounds__(TPB)
hist_kernel(const int* __restrict__ dst, unsigned* __restrict__ blkhist,
            int E, int B, int span) {
    extern __shared__ unsigned h[];
    for (int i = threadIdx.x; i < B; i += blockDim.x) h[i] = 0;
    __syncthreads();
    int start = blockIdx.x * span;
    int end = start + span; if (end > E) end = E;
    for (int e = start + threadIdx.x; e < end; e += blockDim.x)
        atomicAdd(&h[((unsigned)dst[e]) >> SHIFT], 1u);
    __syncthreads();
    for (int i = threadIdx.x; i < B; i += blockDim.x)
        blkhist[(size_t)i * gridDim.x + blockIdx.x] = h[i];  // bucket-major
}

// ---------- pass P1: exclusive scan across blocks, per bucket ----------
__global__ void __launch_bounds__(NBLK)
scan_blocks_kernel(unsigned* __restrict__ blkhist, unsigned* __restrict__ totals) {
    __shared__ unsigned s[NBLK];
    int b = blockIdx.x, t = threadIdx.x;
    unsigned v = blkhist[(size_t)b * NBLK + t];
    s[t] = v; __syncthreads();
    for (int off = 1; off < NBLK; off <<= 1) {
        unsigned add = (t >= off) ? s[t - off] : 0u;
        __syncthreads();
        s[t] += add;
        __syncthreads();
    }
    blkhist[(size_t)b * NBLK + t] = s[t] - v;   // exclusive (local base)
    if (t == NBLK - 1) totals[b] = s[t];
}

// ---------- pass P2: exclusive scan of bucket totals ----------
__global__ void __launch_bounds__(1024)
scan_totals_kernel(const unsigned* __restrict__ totals,
                   unsigned* __restrict__ offsets, int B) {
    __shared__ unsigned s[1024];
    int t = threadIdx.x;
    unsigned v = (t < B) ? totals[t] : 0u;
    s[t] = v; __syncthreads();
    for (int off = 1; off < 1024; off <<= 1) {
        unsigned add = (t >= off) ? s[t - off] : 0u;
        __syncthreads();
        s[t] += add;
        __syncthreads();
    }
    if (t < B) offsets[t] = s[t] - v;
    if (t == B - 1) offsets[B] = s[t];
}

// ---------- pass S: compute payload, place at exact slot (no global atomics) ----------
__global__ void __launch_bounds__(TPB)
scatter_pay_kernel(const float* __restrict__ nl, const float4* __restrict__ nq,
                   const float4* __restrict__ erq, const float* __restrict__ ew,
                   const int* __restrict__ src, const int* __restrict__ dst,
                   const unsigned* __restrict__ blkhist,
                   const unsigned* __restrict__ offsets,
                   uint4* __restrict__ buckets,
                   int E, int B, int span) {
    extern __shared__ unsigned cur[];
    int blk = blockIdx.x, nb = gridDim.x;
    for (int b = threadIdx.x; b < B; b += blockDim.x)
        cur[b] = offsets[b] + blkhist[(size_t)b * nb + blk];
    __syncthreads();
    int start = blk * span;
    int end = start + span; if (end > E) end = E;
    for (int e = start + threadIdx.x; e < end; e += blockDim.x) {
        int s_ = src[e];
        unsigned d = (unsigned)dst[e];
        float l = nl[s_];
        float p = __expf(TEMP * ew[e] * l);
        float ow, ox, oy, oz;
        hamilton(erq[e], nq[s_], ow, ox, oy, oz);
        unsigned slot = atomicAdd(&cur[d >> SHIFT], 1u);  // LDS cursor
        uint4 pk;
        pk.x = (d & (GSZ - 1)) | (f2h(p) << 16);
        pk.y = f2h(p * l)  | (f2h(p * ow) << 16);
        pk.z = f2h(p * ox) | (f2h(p * oy) << 16);
        pk.w = f2h(p * oz);
        buckets[slot] = pk;
    }
}

// ---------- pass G: per-bucket LDS accumulate + finalize ----------
__global__ void __launch_bounds__(TPB)
gather_pay_kernel(const float* __restrict__ nl, const float4* __restrict__ nq,
                  const unsigned* __restrict__ offsets,
                  const uint4* __restrict__ buckets,
                  float4* __restrict__ out_q, float* __restrict__ out_l, int N) {
    __shared__ float acc[GSZ * 7];                 // stride 7: gcd(7,32)=1
    int b = blockIdx.x;
    for (int i = threadIdx.x; i < GSZ * 7; i += blockDim.x) acc[i] = 0.f;
    __syncthreads();
    unsigned s0 = offsets[b], s1 = offsets[b + 1];
    for (unsigned i = s0 + threadIdx.x; i < s1; i += blockDim.x) {
        uint4 pk = buckets[i];
        unsigned dl = pk.x & 0xFFFFu;
        float p  = h2f(pk.x >> 16);
        float pl = h2f(pk.y);
        float q0 = h2f(pk.y >> 16);
        float q1 = h2f(pk.z);
        float q2 = h2f(pk.z >> 16);
        float q3 = h2f(pk.w);
        float* a = &acc[dl * 7];
        atomicAdd(a + 0, p);  atomicAdd(a + 1, pl);
        atomicAdd(a + 2, q0); atomicAdd(a + 3, q1);
        atomicAdd(a + 4, q2); atomicAdd(a + 5, q3);
    }
    __syncthreads();
    int n0 = b * GSZ;
    for (int j = threadIdx.x; j < GSZ; j += blockDim.x) {
        int n = n0 + j;
        if (n >= N) break;
        float l = nl[n];
        float ps = __expf(TEMP * l);
        float* a = &acc[j * 7];
        float Z  = a[0] + ps;
        float sl = a[1] + ps * l;
        float4 q = nq[n];
        float qw = a[2] + ps * q.x;
        float qx = a[3] + ps * q.y;
        float qy = a[4] + ps * q.z;
        float qz = a[5] + ps * q.w;
        float inv = 1.0f / Z;
        qw *= inv; qx *= inv; qy *= inv; qz *= inv;
        float norm = fmaxf(sqrtf(qw*qw + qx*qx + qy*qy + qz*qz), 1e-12f);
        float rn = 1.0f / norm;
        out_q[n] = make_float4(qw * rn, qx * rn, qy * rn, qz * rn);
        out_l[n] = sl * inv;
    }
}

// ---------------- fallback path (R3) ----------------
__global__ void __launch_bounds__(256)
scatter_kernel(const int* __restrict__ dst, int* __restrict__ cnt,
               int* __restrict__ bucket, int cap,
               const float* __restrict__ node_levels, const float4* __restrict__ node_q,
               const float4* __restrict__ edge_rel_q, const float* __restrict__ edge_w,
               const int* __restrict__ src, float* __restrict__ side, int E) {
    int e = blockIdx.x * blockDim.x + threadIdx.x;
    if (e >= E) return;
    int d = dst[e];
    int slot = atomicAdd(&cnt[d], 1);
    if (slot < cap) {
        bucket[(long long)d * cap + slot] = e;
    } else {
        int s = src[e];
        float l = node_levels[s];
        float p = __expf(TEMP * edge_w[e] * l);
        float ow, ox, oy, oz;
        hamilton(edge_rel_q[e], node_q[s], ow, ox, oy, oz);
        float* rec = side + 6 * (long long)d;
        pk_fadd(rec + 0, p,      p * l);
        pk_fadd(rec + 2, p * ow, p * ox);
        pk_fadd(rec + 4, p * oy, p * oz);
    }
}

__global__ void __launch_bounds__(256)
gather_kernel(const float* __restrict__ node_levels, const float4* __restrict__ node_q,
              const float4* __restrict__ edge_rel_q, const float* __restrict__ edge_w,
              const int* __restrict__ src, const int* __restrict__ cnt,
              const int* __restrict__ bucket, int cap, const float* __restrict__ side,
              float4* __restrict__ out_q, float* __restrict__ out_l, int N) {
    int tid  = blockIdx.x * blockDim.x + threadIdx.x;
    int wave = tid >> 6, lane = tid & 63, half = lane >> 5, sub = lane & 31;
    int n = wave * 2 + half;
    float aZ = 0.f, aL = 0.f, a0 = 0.f, a1 = 0.f, a2 = 0.f, a3 = 0.f;
    if (n < N) {
        int deg = cnt[n]; if (deg > cap) deg = cap;
        const int* bkt = bucket + (long long)n * cap;
        for (int s = sub; s < deg; s += 32) {
            int e = bkt[s];
            int sn = src[e];
            float l = node_levels[sn];
            float p = __expf(TEMP * edge_w[e] * l);
            float ow, ox, oy, oz;
            hamilton(edge_rel_q[e], node_q[sn], ow, ox, oy, oz);
            aZ += p; aL += p * l; a0 += p * ow; a1 += p * ox; a2 += p * oy; a3 += p * oz;
        }
    }
    for (int m = 16; m; m >>= 1) {
        aZ += __shfl_xor(aZ, m); aL += __shfl_xor(aL, m);
        a0 += __shfl_xor(a0, m); a1 += __shfl_xor(a1, m);
        a2 += __shfl_xor(a2, m); a3 += __shfl_xor(a3, m);
    }
    if (sub == 0 && n < N) {
        const float* rec = side + 6 * (long long)n;
        float l  = node_levels[n];
        float ps = __expf(TEMP * l);
        float Z  = aZ + rec[0] + ps;
        float sl = aL + rec[1] + ps * l;
        float4 q = node_q[n];
        float qw = a0 + rec[2] + ps * q.x;
        float qx = a1 + rec[3] + ps * q.y;
        float qy = a2 + rec[4] + ps * q.z;
        float qz = a3 + rec[5] + ps * q.w;
        float inv = 1.0f / Z;
        qw *= inv; qx *= inv; qy *= inv; qz *= inv;
        float norm = fmaxf(sqrtf(qw*qw + qx*qx + qy*qy + qz*qz), 1e-12f);
        float rn = 1.0f / norm;
        out_q[n] = make_float4(qw * rn, qx * rn, qy * rn, qz * rn);
        out_l[n] = sl * inv;
    }
}

extern "C" void kernel_launch(void* const* d_in, const int* in_sizes, int n_in,
                              void* d_out, int out_size, void* d_ws, size_t ws_size,
                              hipStream_t stream) {
    const float*  node_levels = (const float*)d_in[0];
    const float4* node_q      = (const float4*)d_in[1];
    const float4* edge_rel_q  = (const float4*)d_in[2];
    const float*  edge_w      = (const float*)d_in[3];
    const int*    src         = (const int*)d_in[4];
    const int*    dst         = (const int*)d_in[5];

    const int N = in_sizes[0];
    const int E = in_sizes[3];

    const int B = (N + GSZ - 1) / GSZ;            // coarse buckets
    const int span = (E + NBLK - 1) / NBLK;       // edges per scatter block

    // ws layout: blkhist[B*NBLK] u32 | totals[B] u32 | offsets[B+1] u32 | pad | buckets[E] uint4
    size_t blkhist_elems = (size_t)B * NBLK;
    size_t totals_off    = blkhist_elems;
    size_t offsets_off   = totals_off + B;
    size_t head_elems    = offsets_off + B + 1;
    size_t buckets_byte  = (head_elems * 4 + 15) & ~(size_t)15;
    size_t need          = buckets_byte + (size_t)E * 16;

    if (need <= ws_size && B <= 1024 && (size_t)B * 4 <= 65536) {
        unsigned* blkhist = (unsigned*)d_ws;
        unsigned* totals  = blkhist + totals_off;
        unsigned* offsets = blkhist + offsets_off;
        uint4*    buckets = (uint4*)((char*)d_ws + buckets_byte);

        hist_kernel<<<NBLK, TPB, B * 4, stream>>>(dst, blkhist, E, B, span);
        scan_blocks_kernel<<<B, NBLK, 0, stream>>>(blkhist, totals);
        scan_totals_kernel<<<1, 1024, 0, stream>>>(totals, offsets, B);
        scatter_pay_kernel<<<NBLK, TPB, B * 4, stream>>>(
            node_levels, node_q, edge_rel_q, edge_w, src, dst,
            blkhist, offsets, buckets, E, B, span);
        gather_pay_kernel<<<B, TPB, 0, stream>>>(
            node_levels, node_q, offsets, buckets,
            (float4*)d_out, (float*)d_out + 4 * (long long)N, N);
    } else {
        // R3 fallback
        const int tpb = 256;
        size_t cnt_elems  = ((size_t)N + 3) & ~(size_t)3;
        size_t side_elems = 6 * (size_t)N;
        size_t head_bytes = (cnt_elems + side_elems) * 4;
        int cap = 0;
        for (int c : {128, 64}) {
            if (head_bytes + (size_t)N * c * 4 <= ws_size) { cap = c; break; }
        }
        int*   cnt    = (int*)d_ws;
        float* side   = (float*)d_ws + cnt_elems;
        int*   bucket = (int*)d_ws + cnt_elems + side_elems;
        hipMemsetAsync(d_ws, 0, head_bytes, stream);
        scatter_kernel<<<(E + tpb - 1) / tpb, tpb, 0, stream>>>(
            dst, cnt, bucket, cap, node_levels, node_q, edge_rel_q, edge_w, src, side, E);
        int waves  = (N + 1) / 2;
        int blocks = (waves * 64 + tpb - 1) / tpb;
        gather_kernel<<<blocks, tpb, 0, stream>>>(
            node_levels, node_q, edge_rel_q, edge_w, src, cnt, bucket, cap, side,
            (float4*)d_out, (float*)d_out + 4 * (long long)N, N);
    }
}